// Round 3
// baseline (448.702 us; speedup 1.0000x reference)
//
#include <hip/hip_runtime.h>
#include <stdint.h>

// LSTM cell, single fused kernel: gates = [x||h] @ W^T + b, bf16 MFMA.
// M=65536 rows, N=1024 (4 gates x 256 h), K=512. A converted fp32->bf16 in-kernel.
// Tile col c in [0,128): gate=(c>>4)&3, h = h0 + (c&15) + 16*(c>>6).
// Wave tile = 32 rows x 128 cols -> one wave owns all 4 gates AND both 16-col
// halves for its rows => register LSTM + full-line vectorized stores.
#define B_DIM 65536
#define HOFF  16777216   // B_DIM*256

typedef __attribute__((ext_vector_type(8))) short short8;
typedef __attribute__((ext_vector_type(8))) unsigned short ushort8_t;
typedef __attribute__((ext_vector_type(4))) float f32x4;

__device__ __forceinline__ unsigned f2bf_u(float f) {   // RNE, result in low 16
  unsigned u = __builtin_bit_cast(unsigned, f);
  u += 0x7FFFu + ((u >> 16) & 1u);
  return u >> 16;
}
__device__ __forceinline__ unsigned pack2(float lo, float hi) {
  return f2bf_u(lo) | (f2bf_u(hi) << 16);
}
__device__ __forceinline__ unsigned short f2bf(float f) { return (unsigned short)f2bf_u(f); }

__device__ __forceinline__ float sigf(float x) { return 1.0f / (1.0f + __expf(-x)); }
__device__ __forceinline__ float tanh_fast(float x) {
  float a = fabsf(x);
  float e = __expf(-2.0f * a);
  float t = (1.0f - e) / (1.0f + e);
  return x < 0.0f ? -t : t;
}

typedef const __attribute__((address_space(1))) unsigned int* as1p;
typedef __attribute__((address_space(3))) unsigned int* as3p;
__device__ __forceinline__ void llds16(const unsigned short* g, unsigned short* l) {
  __builtin_amdgcn_global_load_lds((as1p)g, (as3p)l, 16, 0, 0);
}

// barrier WITHOUT vmcnt drain (keeps prefetch loads in flight across it)
#define SYNC_LGKM() asm volatile("s_waitcnt lgkmcnt(0)\n\ts_barrier" ::: "memory")
#define WAVE_LDS_FENCE() asm volatile("s_waitcnt lgkmcnt(0)" ::: "memory")

// ---- prep: W fp32 -> bf16 n-major [1024][512] (3 MB moved, ~4 us) ----------
__global__ void prep_w(const float* __restrict__ Wi, const float* __restrict__ Wh,
                       ushort8_t* __restrict__ W8) {
  unsigned o = blockIdx.x * 256u + threadIdx.x;   // [0, 1024*64)
  unsigned n = o >> 6, c8 = o & 63u;
  const float* src = (c8 < 32u) ? Wi + (size_t)n * 256u + c8 * 8u
                                : Wh + (size_t)n * 256u + (c8 - 32u) * 8u;
  float4 v0 = *(const float4*)src;
  float4 v1 = *(const float4*)(src + 4);
  ushort8_t p;
  p[0] = f2bf(v0.x); p[1] = f2bf(v0.y); p[2] = f2bf(v0.z); p[3] = f2bf(v0.w);
  p[4] = f2bf(v1.x); p[5] = f2bf(v1.y); p[6] = f2bf(v1.z); p[7] = f2bf(v1.w);
  W8[o] = p;
}

// ---- fused: convert A + GEMM + LSTM + vectorized store ---------------------
__global__ __launch_bounds__(256, 3) void lstm_fused(
    const float* __restrict__ X, const float* __restrict__ Hs,
    const unsigned short* __restrict__ W,     // [1024][512] bf16 (ws)
    const float* __restrict__ cprev,
    const float* __restrict__ bi, const float* __restrict__ bh,
    float* __restrict__ out) {
  __shared__ union {
    struct { unsigned short A[128 * 32]; unsigned short B[2][128 * 32]; } s; // 8+16 KB
    float ep[4 * 1152];                                                      // 18 KB
  } sm;

  const int t = threadIdx.x;
  const int wid = t >> 6, lane = t & 63;
  const int m = lane & 15, q = lane >> 4;
  const int b0 = (int)(blockIdx.x >> 3) * 128;  // 8 consecutive blocks (=8 XCDs) share A rows
  const int h0 = (int)(blockIdx.x & 7) * 32;
  const int R = wid * 32;                        // wave's row offset in tile

  // B staging: 8 segs of 1KB (16 cols x 64B); wave stages segs {2w, 2w+1}
  const int l4 = lane >> 2;
  const int sg0 = wid * 2, sg1 = sg0 + 1;
  const int c0 = sg0 * 16 + l4, c1 = sg1 * 16 + l4;
  const int ckb = ((lane & 3) ^ ((l4 >> 1) & 3)) * 8;   // XOR-swizzled k-chunk
  const int n0 = (((c0 >> 4) & 3) << 8) + h0 + (c0 & 15) + ((c0 >> 6) << 4);
  const int n1 = (((c1 >> 4) & 3) << 8) + h0 + (c1 & 15) + ((c1 >> 6) << 4);
  const unsigned wO0 = (unsigned)n0 * 512u + (unsigned)ckb;
  const unsigned wO1 = (unsigned)n1 * 512u + (unsigned)ckb;

  // A staging: thread -> (row ar, half hf): 16 fp32 -> 16 bf16 -> 2 swizzled b128
  const int ar = t >> 1, hf = t & 1;
  const unsigned aoff = (unsigned)(b0 + ar) * 256u + (unsigned)hf * 16u;  // floats
  const int slot0 = (2 * hf) ^ ((ar >> 1) & 3), slot1 = slot0 ^ 1;
  uint4* dA0 = (uint4*)&sm.s.A[ar * 32 + slot0 * 8];
  uint4* dA1 = (uint4*)&sm.s.A[ar * 32 + slot1 * 8];

  const int swzb = (q ^ ((m >> 1) & 3)) * 8;            // frag-read slot (ushorts)
  const unsigned short* aRd = &sm.s.A[(R + m) * 32 + swzb];
  const int bRdOff = m * 32 + swzb;

  // accumulators pre-seeded with bias
  f32x4 acc[2][8];
#pragma unroll
  for (int jj = 0; jj < 8; ++jj) {
    int g = jj & 3, hcol = h0 + ((jj >> 2) << 4) + m;
    float bvv = bi[(g << 8) + hcol] + bh[(g << 8) + hcol];
    f32x4 z = {bvv, bvv, bvv, bvv};
    acc[0][jj] = z; acc[1][jj] = z;
  }

  // preload kt=0
  float4 a0, a1, a2, a3;
  { const float* p = X + aoff;
    a0 = *(const float4*)p;       a1 = *(const float4*)(p + 4);
    a2 = *(const float4*)(p + 8); a3 = *(const float4*)(p + 12); }
  llds16(W + wO0, &sm.s.B[0][sg0 * 512]);
  llds16(W + wO1, &sm.s.B[0][sg1 * 512]);

#pragma unroll 2
  for (int kt = 0; kt < 16; ++kt) {
    const int cur = kt & 1, nxt = cur ^ 1;
    // convert + write A(kt)  [compiler emits vmcnt(0) here -> also drains B llds(kt)]
    uint4 u0, u1;
    u0.x = pack2(a0.x, a0.y); u0.y = pack2(a0.z, a0.w);
    u0.z = pack2(a1.x, a1.y); u0.w = pack2(a1.z, a1.w);
    u1.x = pack2(a2.x, a2.y); u1.y = pack2(a2.z, a2.w);
    u1.z = pack2(a3.x, a3.y); u1.w = pack2(a3.z, a3.w);
    *dA0 = u0; *dA1 = u1;
    __syncthreads();                       // A(kt)+B(kt) visible
    if (kt < 15) {                         // B(kt+1) -> other buffer (in flight past SYNC_LGKM)
      llds16(W + wO0 + (unsigned)(kt + 1) * 32u, &sm.s.B[nxt][sg0 * 512]);
      llds16(W + wO1 + (unsigned)(kt + 1) * 32u, &sm.s.B[nxt][sg1 * 512]);
    }
    short8 av[2], bv[8];
    av[0] = *(const short8*)aRd;
    av[1] = *(const short8*)(aRd + 16 * 32);
#pragma unroll
    for (int jj = 0; jj < 8; ++jj)
      bv[jj] = *(const short8*)&sm.s.B[cur][jj * 512 + bRdOff];
    if (kt < 15) {                         // A(kt+1) -> regs (in flight past SYNC_LGKM)
      const float* src = ((kt + 1) < 8) ? X : Hs;
      const float* p = src + aoff + ((unsigned)(kt + 1) & 7u) * 32u;
      a0 = *(const float4*)p;       a1 = *(const float4*)(p + 4);
      a2 = *(const float4*)(p + 8); a3 = *(const float4*)(p + 12);
    }
    SYNC_LGKM();                           // reads done; NO vmcnt drain
#pragma unroll
    for (int i = 0; i < 2; ++i)
#pragma unroll
      for (int jj = 0; jj < 8; ++jj)
        acc[i][jj] = __builtin_amdgcn_mfma_f32_16x16x32_bf16(av[i], bv[jj], acc[i][jj], 0, 0, 0);
  }

  // ---- epilogue: register LSTM, per-wave LDS transpose, float4 stores ------
  // wave-private region (no barriers needed after final SYNC_LGKM)
  float* EB = sm.ep + wid * 1152;          // h: [lrow*36+col], c: +576
  const int ROWB = b0 + R;
#pragma unroll
  for (int i = 0; i < 2; ++i) {
#pragma unroll
    for (int ch = 0; ch < 2; ++ch)
#pragma unroll
      for (int r = 0; r < 4; ++r) {
        int row = ROWB + i * 16 + q * 4 + r;
        float cv = cprev[(size_t)row * 256 + h0 + ch * 16 + m];
        float iv = sigf(acc[i][ch * 4 + 0][r]);
        float fv = sigf(acc[i][ch * 4 + 1][r]);
        float gv = tanh_fast(acc[i][ch * 4 + 2][r]);
        float ov = sigf(acc[i][ch * 4 + 3][r]);
        float cn = fv * cv + iv * gv;
        float hn = ov * tanh_fast(cn);
        int lrow = q * 4 + r, col = ch * 16 + m;
        EB[lrow * 36 + col] = hn;
        EB[576 + lrow * 36 + col] = cn;
      }
    WAVE_LDS_FENCE();                      // writes visible within wave
    int lr = lane & 15, cb = (lane >> 4) * 8;
    float4 hv0 = *(const float4*)&EB[lr * 36 + cb];
    float4 hv1 = *(const float4*)&EB[lr * 36 + cb + 4];
    float4 cv0 = *(const float4*)&EB[576 + lr * 36 + cb];
    float4 cv1 = *(const float4*)&EB[576 + lr * 36 + cb + 4];
    size_t gro = (size_t)(ROWB + i * 16 + lr) * 256 + h0 + cb;
    *(float4*)&out[gro] = hv0;
    *(float4*)&out[gro + 4] = hv1;
    *(float4*)&out[HOFF + gro] = cv0;
    *(float4*)&out[HOFF + gro + 4] = cv1;
    if (i == 0) WAVE_LDS_FENCE();          // reads done before pass-1 overwrite
  }
}

// ---- fallback (tiny workspace): correct but slow fp32 path -----------------
__global__ void lstm_naive(const float* __restrict__ x, const float* __restrict__ h,
                           const float* __restrict__ c,
                           const float* __restrict__ Wi, const float* __restrict__ Wh,
                           const float* __restrict__ bi, const float* __restrict__ bh,
                           float* __restrict__ out) {
  int gid = blockIdx.x * 256 + threadIdx.x;
  int b = gid >> 8, hh = gid & 255;
  float a0 = bi[hh] + bh[hh];
  float a1 = bi[256 + hh] + bh[256 + hh];
  float a2 = bi[512 + hh] + bh[512 + hh];
  float a3 = bi[768 + hh] + bh[768 + hh];
  const float* xr = x + (size_t)b * 256;
  const float* hr = h + (size_t)b * 256;
  const float* w0 = Wi + (size_t)hh * 256;
  const float* w1 = Wh + (size_t)hh * 256;
  for (int i = 0; i < 256; ++i) {
    float xv = xr[i];
    a0 += xv * w0[i]; a1 += xv * w0[65536 + i];
    a2 += xv * w0[131072 + i]; a3 += xv * w0[196608 + i];
  }
  for (int i = 0; i < 256; ++i) {
    float hv = hr[i];
    a0 += hv * w1[i]; a1 += hv * w1[65536 + i];
    a2 += hv * w1[131072 + i]; a3 += hv * w1[196608 + i];
  }
  float iv = sigf(a0), fv = sigf(a1), gv = tanh_fast(a2), ov = sigf(a3);
  float cn = fv * c[gid] + iv * gv;
  out[gid] = ov * tanh_fast(cn);
  out[HOFF + gid] = cn;
}

extern "C" void kernel_launch(void* const* d_in, const int* in_sizes, int n_in,
                              void* d_out, int out_size, void* d_ws, size_t ws_size,
                              hipStream_t stream) {
  const float* x  = (const float*)d_in[0];
  const float* h  = (const float*)d_in[1];
  const float* c  = (const float*)d_in[2];
  const float* Wi = (const float*)d_in[3];
  const float* Wh = (const float*)d_in[4];
  const float* bi = (const float*)d_in[5];
  const float* bh = (const float*)d_in[6];
  float* out = (float*)d_out;

  const size_t needW = (size_t)1024 * 512 * 2;   // 1 MB bf16 W
  if (ws_size >= needW) {
    ushort8_t* W8 = (ushort8_t*)d_ws;
    hipLaunchKernelGGL(prep_w, dim3(1024 * 64 / 256), dim3(256), 0, stream, Wi, Wh, W8);
    hipLaunchKernelGGL(lstm_fused, dim3((B_DIM / 128) * 8), dim3(256), 0, stream,
                       x, h, (const unsigned short*)W8, c, bi, bh, out);
  } else {
    hipLaunchKernelGGL(lstm_naive, dim3(B_DIM), dim3(256), 0, stream,
                       x, h, c, Wi, Wh, bi, bh, out);
  }
}